// Round 8
// baseline (209.346 us; speedup 1.0000x reference)
//
#include <hip/hip_runtime.h>
#include <cstdint>

#pragma clang fp contract(off)

#define NB      32
#define NC      18
#define NA      8400
#define NCH     (4 + NC)
#define TOPK    300
#define TARGET  316        // TOPK + margin: absorbs sigmoid-tie rank ambiguity
#define NBINS   2048
#define CAP     1024
#define CONF    0.25f
#define IOU_T   0.45f
#define NT      128
#define NW      (NT / 64)
// Prefilter: N(0,1) logits, top-316 cutoff ~1.75 +- 0.1; count(x>1.4) in [553,803] (5-sigma).
// Fast path requires TARGET <= s_cnt <= CAP, else exact fallback.
#define PREF_X  1.4f
// sigmoid(x) > 0.25  <=>  x > -ln(3). Outside [XLO,XHI] analytic compare is exact.
#define XHI     (-1.0984f)
#define XLO     (-1.0988f)

// Fast-path binning: keys (mono_key of x>1.4) start at 0xBFB33333.
#define FAST_KBASE 0xBFB00000u
#define FAST_SHIFT 14
// Fallback binning: conf_pass keys start ~0x40735C26.
#define FB_KBASE   0x40000000u
#define FB_SHIFT   21

typedef unsigned long long ull;

__device__ __forceinline__ float sigmoidf(float x) {
    return 1.0f / (1.0f + expf(-x));
}
__device__ __forceinline__ unsigned int mono_key(unsigned int bits) {
    return (bits & 0x80000000u) ? ~bits : (bits | 0x80000000u);
}
__device__ __forceinline__ unsigned int mono_inv(unsigned int key) {
    return (key & 0x80000000u) ? (key ^ 0x80000000u) : ~key;
}
__device__ __forceinline__ bool conf_pass(float x) {
    if (x >= XHI) return true;
    if (x <= XLO) return false;
    return sigmoidf(x) > CONF;   // rare exact band (~1 element per task)
}
__device__ __forceinline__ unsigned int make_key(float x) {
    return conf_pass(x) ? mono_key(__float_as_uint(x)) : 0u;
}
__device__ __forceinline__ ull readlane64(ull v, int i) {
    unsigned lo = (unsigned)__builtin_amdgcn_readlane((int)(unsigned)(v & 0xFFFFFFFFull), i);
    unsigned hi = (unsigned)__builtin_amdgcn_readlane((int)(unsigned)(v >> 32), i);
    return ((ull)hi << 32) | (ull)lo;
}

// Suffix-find over hist: T1 s.t. count(bins > T1) < target <= count(bins >= T1).
// Requires *s_T1 == -1 on entry. Contains barriers (block-uniform flow only).
__device__ __forceinline__ void suffix_find(unsigned int* hist, unsigned int* wtot,
                                            int target, int tid, int* s_T1) {
    const int base = tid * (NBINS / NT);   // 16 bins per thread
    unsigned int v = 0;
#pragma unroll
    for (int k = 0; k < NBINS / NT; ++k) v += hist[base + k];
    const int lane = tid & 63;
    unsigned int s = v;   // inclusive suffix sum within wave
#pragma unroll
    for (int d = 1; d < 64; d <<= 1) {
        unsigned int o = __shfl_down(s, d, 64);
        if (lane + d < 64) s += o;
    }
    if (lane == 0) wtot[tid >> 6] = s;
    __syncthreads();
    unsigned int above_waves = 0;
    for (int wv = (tid >> 6) + 1; wv < NW; ++wv) above_waves += wtot[wv];
    unsigned int acc = (s - v) + above_waves;  // strictly after this thread's chunk
    for (int bin = base + (NBINS / NT) - 1; bin >= base; --bin) {
        unsigned int cnt = hist[bin];
        if (acc < (unsigned int)target && acc + cnt >= (unsigned int)target) *s_T1 = bin;
        acc += cnt;
    }
    __syncthreads();
}

// LDS pool phase-aliasing map (17.6 KB):
//  [0,8192):      hist (P0..suffix) -> cand2 (P4..P5b) -> sup[0:8192) (P7..P8)
//  [8192,16384):  cand (P1..P4) -> skey@8192 (P5b..P6a) -> sup[8192:12000) (P7..P8)
//  [12000,16800): box4 (P6a..P9)
//  [16800,18000): bvv  (P6a..P9)
#define OFF_CAND   8192
#define OFF_SKEY   8192
#define OFF_SUP    0
#define OFF_BOX4   12000
#define OFF_BVV    16800
#define POOL_BYTES 18000

__global__ __launch_bounds__(NT) void yolo_post(const float* __restrict__ in,
                                                float* __restrict__ out) {
    __shared__ __align__(16) unsigned char pool[POOL_BYTES];
    __shared__ unsigned int wtot[NW];
    __shared__ ull keepw[5];
    __shared__ unsigned int s_cnt, s_cnt2;
    __shared__ int s_T1;

    unsigned int* hist = (unsigned int*)pool;
    ull*  cand2 = (ull*)pool;
    ull*  cand  = (ull*)(pool + OFF_CAND);
    ull*  skey  = (ull*)(pool + OFF_SKEY);
    ull*  sup   = (ull*)(pool + OFF_SUP);    // [300][5]
    float4* box4 = (float4*)(pool + OFF_BOX4);
    float*  bvv  = (float*)(pool + OFF_BVV);

    const int tid = threadIdx.x;
    const int lane = tid & 63;
    const ull ltm = (1ull << lane) - 1ull;
    // XCD swizzle: image b -> XCD b%8 (round-robin dispatch over 8 XCDs)
    const int x = blockIdx.x;
    const int b = (x & 7) + 8 * ((x >> 3) & 3);
    const int c = x >> 5;
    const float* cls = in + (size_t)b * NCH * NA + (size_t)(4 + c) * NA;
    const float* box = in + (size_t)b * NCH * NA;

    // ---- P0: zero hist (uint4), init counters ----
    {
        uint4* h4 = (uint4*)hist;
#pragma unroll
        for (int i = 0; i < (NBINS / 4) / NT; ++i)
            h4[tid + NT * i] = uint4{0u, 0u, 0u, 0u};
    }
    if (tid == 0) { s_cnt = 0; s_cnt2 = 0; s_T1 = -1; }
    __syncthreads();

    // ---- P1: global pass, prefilter x>1.4, wave-aggregated compaction into cand.
    //      Explicit 4-deep load prefetch per batch. ----
    {
        const float4* cls4 = (const float4*)cls;
        auto do_quad = [&](float4 v, unsigned int i0) {
            float xs[4] = {v.x, v.y, v.z, v.w};
            ull mq[4];
            unsigned int cnt = 0;
#pragma unroll
            for (int t = 0; t < 4; ++t) {
                mq[t] = __ballot(xs[t] > PREF_X);
                cnt += (unsigned int)__popcll(mq[t]);
            }
            if (cnt) {
                unsigned int basep = 0;
                if (lane == 0) basep = atomicAdd(&s_cnt, cnt);
                basep = (unsigned int)__builtin_amdgcn_readfirstlane((int)basep);
                unsigned int pre = 0;
#pragma unroll
                for (int t = 0; t < 4; ++t) {
                    if (xs[t] > PREF_X) {
                        unsigned int p = basep + pre + (unsigned int)__popcll(mq[t] & ltm);
                        if (p < CAP)
                            cand[p] = ((ull)mono_key(__float_as_uint(xs[t])) << 32) |
                                      (ull)(~(i0 + t));
                    }
                    pre += (unsigned int)__popcll(mq[t]);
                }
            }
        };
#pragma unroll
        for (int m = 0; m < 4; ++m) {
            float4 v[4];
#pragma unroll
            for (int u = 0; u < 4; ++u) v[u] = cls4[tid + NT * (4 * m + u)];
#pragma unroll
            for (int u = 0; u < 4; ++u)
                do_quad(v[u], (unsigned int)(tid + NT * (4 * m + u)) * 4u);
        }
        if (tid < NA / 4 - 2048) {   // 52-quad tail (wave 0 only)
            do_quad(cls4[2048 + tid], (unsigned int)(2048 + tid) * 4u);
        }
    }
    __syncthreads();

    const int pcnt = (int)s_cnt;
    if (pcnt >= TARGET && pcnt <= CAP) {
        // ======== FAST PATH ========
        // ---- P2: refine histogram over prefiltered candidates ----
        for (int e = tid; e < pcnt; e += NT) {
            unsigned int k32 = (unsigned int)(cand[e] >> 32);
            atomicAdd(&hist[min((k32 - FAST_KBASE) >> FAST_SHIFT, (unsigned)(NBINS - 1))], 1u);
        }
        __syncthreads();
        suffix_find(hist, wtot, TARGET, tid, &s_T1);
        // ---- P4: compact selected -> cand2 with FUSED exact-sigmoid rekey,
        //      wave-aggregated counter ----
        {
            const ull thr = ((ull)FAST_KBASE + ((ull)(unsigned int)s_T1 << FAST_SHIFT)) << 32;
            const int iters = (pcnt + NT - 1) / NT;
            for (int it = 0; it < iters; ++it) {
                int e = tid + it * NT;
                bool act = e < pcnt;
                ull k = act ? cand[e] : 0ull;
                bool sel = act && (k >= thr);
                ull mb = __ballot(sel);
                unsigned int cnt = (unsigned int)__popcll(mb);
                if (cnt) {
                    unsigned int basep = 0;
                    if (lane == 0) basep = atomicAdd(&s_cnt2, cnt);
                    basep = (unsigned int)__builtin_amdgcn_readfirstlane((int)basep);
                    if (sel) {
                        float xv = __uint_as_float(mono_inv((unsigned int)(k >> 32)));
                        float sv = sigmoidf(xv);
                        unsigned int p = basep + (unsigned int)__popcll(mb & ltm);
                        if (p < CAP)
                            cand2[p] = ((ull)__float_as_uint(sv) << 32) |
                                       (k & 0xFFFFFFFFull);
                    }
                }
            }
        }
        __syncthreads();
    } else {
        // ======== EXACT FALLBACK (rare) ========
        {
            const float4* cls4 = (const float4*)cls;
            for (int q = tid; q < NA / 4; q += NT) {
                float4 v = cls4[q];
                unsigned int kx = make_key(v.x), ky = make_key(v.y);
                unsigned int kz = make_key(v.z), kw = make_key(v.w);
                if (kx) atomicAdd(&hist[min((kx - FB_KBASE) >> FB_SHIFT, (unsigned)(NBINS - 1))], 1u);
                if (ky) atomicAdd(&hist[min((ky - FB_KBASE) >> FB_SHIFT, (unsigned)(NBINS - 1))], 1u);
                if (kz) atomicAdd(&hist[min((kz - FB_KBASE) >> FB_SHIFT, (unsigned)(NBINS - 1))], 1u);
                if (kw) atomicAdd(&hist[min((kw - FB_KBASE) >> FB_SHIFT, (unsigned)(NBINS - 1))], 1u);
            }
        }
        __syncthreads();
        suffix_find(hist, wtot, TARGET, tid, &s_T1);
        {
            const ull thr = (s_T1 < 0) ? 0ull
                : ((ull)FB_KBASE + ((ull)(unsigned int)s_T1 << FB_SHIFT));
            const float4* cls4 = (const float4*)cls;
            for (int q = tid; q < NA / 4; q += NT) {
                float4 v = cls4[q];
                const unsigned int i0 = (unsigned int)q * 4u;
                float xs[4] = {v.x, v.y, v.z, v.w};
#pragma unroll
                for (int t = 0; t < 4; ++t) {
                    unsigned int d = make_key(xs[t]);
                    if (d && (ull)d >= thr) {
                        unsigned int p = atomicAdd(&s_cnt2, 1u);
                        if (p < CAP) {
                            float sv = sigmoidf(xs[t]);
                            cand2[p] = ((ull)__float_as_uint(sv) << 32) |
                                       (ull)(~(i0 + t));
                        }
                    }
                }
            }
        }
        __syncthreads();
    }

    const int F = min((int)s_cnt2, CAP);
    const int numSel = min(F, TOPK);

    // ---- P5b: rank-by-counting sort, 4-key register blocking (covers F<=512;
    //      residual loop handles rare F>512) ----
    {
        ull kx[4];
        int rk[4];
#pragma unroll
        for (int j = 0; j < 4; ++j) {
            int e = tid + NT * j;
            kx[j] = (e < F) ? cand2[e] : 0ull;
            rk[j] = 0;
        }
        int o = 0;
        for (; o + 4 <= F; o += 4) {
            ulonglong2 p0 = *(const ulonglong2*)&cand2[o];
            ulonglong2 p1 = *(const ulonglong2*)&cand2[o + 2];
#pragma unroll
            for (int j = 0; j < 4; ++j)
                rk[j] += (p0.x > kx[j]) + (p0.y > kx[j]) + (p1.x > kx[j]) + (p1.y > kx[j]);
        }
        for (; o < F; ++o) {
            ull kk = cand2[o];
#pragma unroll
            for (int j = 0; j < 4; ++j) rk[j] += (kk > kx[j]) ? 1 : 0;
        }
        __syncthreads();   // all reads of cand2 done before skey (disjoint) written? skey disjoint; barrier for safety of residual path ordering
#pragma unroll
        for (int j = 0; j < 4; ++j) {
            int e = tid + NT * j;
            if (e < F && rk[j] < TOPK) skey[rk[j]] = kx[j];
        }
        for (int e = 4 * NT + tid; e < F; e += NT) {   // rare residual
            ull kk = cand2[e];
            int r = 0;
            for (int o2 = 0; o2 < F; ++o2) r += (cand2[o2] > kk) ? 1 : 0;
            if (r < TOPK) skey[r] = kk;
        }
    }
    __syncthreads();

    // ---- P6a: gather boxes (cxcywh -> xyxy) as float4 ----
    for (int r = tid; r < numSel; r += NT) {
        ull k = skey[r];
        unsigned int i = ~(unsigned int)(k & 0xFFFFFFFFull);
        float cx = box[i];
        float cy = box[NA + i];
        float w  = box[2 * NA + i];
        float h  = box[3 * NA + i];
        float hw = w * 0.5f, hh = h * 0.5f;
        box4[r] = float4{cx - hw, cy - hh, cx + hw, cy + hh};
        bvv[r] = __uint_as_float((unsigned int)(k >> 32));
    }
    __syncthreads();   // skey consumed; sup region (aliases skey/cand2) now writable

    // ---- P7: suppression masks; full-row writes (incl. zero words -> no pre-zero
    //      pass). Columns cached in const-indexed registers. ----
    {
        const int wave = tid >> 6;
        float4 cb[5];
        float ca[5];
#pragma unroll
        for (int w = 0; w < 5; ++w) {
            int j = (w << 6) + lane;
            float4 v = (j < numSel) ? box4[j] : float4{0.f, 0.f, 0.f, 0.f};
            cb[w] = v;
            ca[w] = fmaxf(v.z - v.x, 0.0f) * fmaxf(v.w - v.y, 0.0f);
        }
        for (int i = wave; i < numSel; i += NW) {
            float4 bi = box4[i];
            float ai = fmaxf(bi.z - bi.x, 0.0f) * fmaxf(bi.w - bi.y, 0.0f);
            const int w0 = i >> 6;   // wave-uniform
#pragma unroll
            for (int w = 0; w < 5; ++w) {
                ull bal = 0ull;
                if (w >= w0) {       // uniform branch
                    const int j = (w << 6) + lane;
                    bool supb = false;
                    if (j < numSel && j > i) {
                        float xx1 = fmaxf(bi.x, cb[w].x);
                        float yy1 = fmaxf(bi.y, cb[w].y);
                        float xx2 = fminf(bi.z, cb[w].z);
                        float yy2 = fminf(bi.w, cb[w].w);
                        float iw = fmaxf(xx2 - xx1, 0.0f);
                        float ih = fmaxf(yy2 - yy1, 0.0f);
                        float inter = iw * ih;
                        float un = ai + ca[w] - inter;
                        float iou = inter / fmaxf(un, 1e-9f);
                        supb = iou > IOU_T;
                    }
                    bal = __ballot(supb);
                }
                if (lane == 0) sup[i * 5 + w] = bal;
            }
        }
    }
    __syncthreads();

    // ---- P8: greedy scan, wave 0, register-resident via readlane broadcast.
    //      rem uniform across lanes; no LDS / branches in hot loop. ----
    if (tid < 64) {
        ull rem[5] = {0ull, 0ull, 0ull, 0ull, 0ull};
#pragma unroll
        for (int w = 0; w < 5; ++w) {
            int r = (w << 6) + lane;
            bool valid = r < numSel;
            ull a0 = valid ? sup[r * 5 + 0] : 0ull;
            ull a1 = valid ? sup[r * 5 + 1] : 0ull;
            ull a2 = valid ? sup[r * 5 + 2] : 0ull;
            ull a3 = valid ? sup[r * 5 + 3] : 0ull;
            ull a4 = valid ? sup[r * 5 + 4] : 0ull;
            int nIn = numSel - (w << 6);
            nIn = nIn < 0 ? 0 : (nIn > 64 ? 64 : nIn);
            for (int i = 0; i < nIn; ++i) {
                if (!((rem[w] >> i) & 1ull)) {   // uniform (rem identical on all lanes)
                    rem[0] |= readlane64(a0, i);
                    rem[1] |= readlane64(a1, i);
                    rem[2] |= readlane64(a2, i);
                    rem[3] |= readlane64(a3, i);
                    rem[4] |= readlane64(a4, i);
                }
            }
            if (lane == 0) keepw[w] = ~rem[w];
        }
    }
    __syncthreads();

    // ---- P9: write output rows (3x float2 per row) ----
    float* outp = out + ((size_t)b * NC + c) * (TOPK * 6);
    for (int r = tid; r < TOPK; r += NT) {
        float x1 = 0.f, y1 = 0.f, x2 = 0.f, y2 = 0.f, vv = 0.f, cc = 0.f;
        if (r < numSel && ((keepw[r >> 6] >> (r & 63)) & 1ull)) {
            float4 bb = box4[r];
            x1 = bb.x; y1 = bb.y; x2 = bb.z; y2 = bb.w;
            vv = bvv[r]; cc = (float)c;
        }
        float* row = outp + r * 6;
        *(float2*)(row)     = float2{x1, y1};
        *(float2*)(row + 2) = float2{x2, y2};
        *(float2*)(row + 4) = float2{vv, cc};
    }
}

extern "C" void kernel_launch(void* const* d_in, const int* in_sizes, int n_in,
                              void* d_out, int out_size, void* d_ws, size_t ws_size,
                              hipStream_t stream) {
    const float* in = (const float*)d_in[0];
    float* out = (float*)d_out;
    yolo_post<<<NB * NC, NT, 0, stream>>>(in, out);
}

// Round 9
// 159.651 us; speedup vs baseline: 1.3113x; 1.3113x over previous
//
#include <hip/hip_runtime.h>
#include <cstdint>

#pragma clang fp contract(off)

#define NB      32
#define NC      18
#define NA      8400
#define NCH     (4 + NC)
#define TOPK    300
#define TARGET  316        // TOPK + margin: absorbs sigmoid-tie rank ambiguity
#define NBINS   2048
#define CAP     1024
#define CONF    0.25f
#define IOU_T   0.45f
#define NT      512
#define NW      (NT / 64)
// Prefilter: N(0,1) logits, top-316 cutoff ~1.75 +- 0.1; count(x>1.4) in [553,803] (5-sigma).
// Fast path requires TARGET <= s_cnt <= CAP, else exact fallback.
#define PREF_X  1.4f
// sigmoid(x) > 0.25  <=>  x > -ln(3). Outside [XLO,XHI] analytic compare is exact.
#define XHI     (-1.0984f)
#define XLO     (-1.0988f)

// Fast-path binning: keys (mono_key of x>1.4) start at 0xBFB33333.
#define FAST_KBASE 0xBFB00000u
#define FAST_SHIFT 14
// Fallback binning: conf_pass keys start ~0x40735C26.
#define FB_KBASE   0x40000000u
#define FB_SHIFT   21

typedef unsigned long long ull;

__device__ __forceinline__ float sigmoidf(float x) {
    return 1.0f / (1.0f + expf(-x));
}
__device__ __forceinline__ unsigned int mono_key(unsigned int bits) {
    return (bits & 0x80000000u) ? ~bits : (bits | 0x80000000u);
}
__device__ __forceinline__ unsigned int mono_inv(unsigned int key) {
    return (key & 0x80000000u) ? (key ^ 0x80000000u) : ~key;
}
__device__ __forceinline__ bool conf_pass(float x) {
    if (x >= XHI) return true;
    if (x <= XLO) return false;
    return sigmoidf(x) > CONF;   // rare exact band (~1 element per task)
}
__device__ __forceinline__ unsigned int make_key(float x) {
    return conf_pass(x) ? mono_key(__float_as_uint(x)) : 0u;
}
__device__ __forceinline__ ull readlane64(ull v, int i) {
    unsigned lo = (unsigned)__builtin_amdgcn_readlane((int)(unsigned)(v & 0xFFFFFFFFull), i);
    unsigned hi = (unsigned)__builtin_amdgcn_readlane((int)(unsigned)(v >> 32), i);
    return ((ull)hi << 32) | (ull)lo;
}

// Suffix-find over hist: T1 s.t. count(bins > T1) < target <= count(bins >= T1).
// Requires *s_T1 == -1 on entry. Contains barriers (block-uniform flow only).
__device__ __forceinline__ void suffix_find(unsigned int* hist, unsigned int* wtot,
                                            int target, int tid, int* s_T1) {
    const int base = tid * (NBINS / NT);   // 4 bins per thread
    unsigned int v = 0;
#pragma unroll
    for (int k = 0; k < NBINS / NT; ++k) v += hist[base + k];
    const int lane = tid & 63;
    unsigned int s = v;   // inclusive suffix sum within wave
#pragma unroll
    for (int d = 1; d < 64; d <<= 1) {
        unsigned int o = __shfl_down(s, d, 64);
        if (lane + d < 64) s += o;
    }
    if (lane == 0) wtot[tid >> 6] = s;
    __syncthreads();
    unsigned int above_waves = 0;
    for (int wv = (tid >> 6) + 1; wv < NW; ++wv) above_waves += wtot[wv];
    unsigned int acc = (s - v) + above_waves;  // strictly after this thread's chunk
    for (int bin = base + (NBINS / NT) - 1; bin >= base; --bin) {
        unsigned int cnt = hist[bin];
        if (acc < (unsigned int)target && acc + cnt >= (unsigned int)target) *s_T1 = bin;
        acc += cnt;
    }
    __syncthreads();
}

// LDS pool phase-aliasing map (17.6 KB):
//  [0,8192):      hist (P0..suffix) -> cand2 (P4..P5b) -> sup[0:8192) (P6b..P8)
//  [8192,16384):  cand (P1..P4) -> skey@8192 (P5b..P6a) -> sup[8192:12000) (P6b..P8)
//  [12000,16800): box4 (P6a..P9)
//  [16800,18000): bvv  (P6a..P9)
#define OFF_CAND   8192
#define OFF_SKEY   8192
#define OFF_SUP    0
#define OFF_BOX4   12000
#define OFF_BVV    16800
#define POOL_BYTES 18000

__global__ __launch_bounds__(NT) void yolo_post(const float* __restrict__ in,
                                                float* __restrict__ out) {
    __shared__ __align__(16) unsigned char pool[POOL_BYTES];
    __shared__ unsigned int wtot[NW];
    __shared__ ull keepw[5];
    __shared__ unsigned int s_cnt, s_cnt2;
    __shared__ int s_T1;

    unsigned int* hist = (unsigned int*)pool;
    ull*  cand2 = (ull*)pool;
    ull*  cand  = (ull*)(pool + OFF_CAND);
    ull*  skey  = (ull*)(pool + OFF_SKEY);
    ull*  sup   = (ull*)(pool + OFF_SUP);    // [300][5]
    float4* box4 = (float4*)(pool + OFF_BOX4);
    float*  bvv  = (float*)(pool + OFF_BVV);

    const int tid = threadIdx.x;
    const int lane = tid & 63;
    const ull ltm = (1ull << lane) - 1ull;
    // XCD swizzle: image b -> XCD b%8 (round-robin dispatch over 8 XCDs)
    const int x = blockIdx.x;
    const int b = (x & 7) + 8 * ((x >> 3) & 3);
    const int c = x >> 5;
    const float* cls = in + (size_t)b * NCH * NA + (size_t)(4 + c) * NA;
    const float* box = in + (size_t)b * NCH * NA;

    // ---- P0: zero hist, init counters ----
    for (int i = tid; i < NBINS; i += NT) hist[i] = 0;
    if (tid == 0) { s_cnt = 0; s_cnt2 = 0; s_T1 = -1; }
    __syncthreads();

    // ---- P1: global pass, prefilter x>1.4, wave-aggregated compaction into cand ----
    {
        const float4* cls4 = (const float4*)cls;
        for (int q = tid; q < NA / 4; q += NT) {
            float4 v = cls4[q];
            const unsigned int i0 = (unsigned int)q * 4u;
            float xs[4] = {v.x, v.y, v.z, v.w};
            ull m[4];
            unsigned int cnt = 0;
#pragma unroll
            for (int t = 0; t < 4; ++t) {
                m[t] = __ballot(xs[t] > PREF_X);
                cnt += (unsigned int)__popcll(m[t]);
            }
            if (cnt) {
                unsigned int base = 0;
                if (lane == 0) base = atomicAdd(&s_cnt, cnt);
                base = (unsigned int)__builtin_amdgcn_readfirstlane((int)base);
                unsigned int pre = 0;
#pragma unroll
                for (int t = 0; t < 4; ++t) {
                    if (xs[t] > PREF_X) {
                        unsigned int p = base + pre + (unsigned int)__popcll(m[t] & ltm);
                        if (p < CAP)
                            cand[p] = ((ull)mono_key(__float_as_uint(xs[t])) << 32) |
                                      (ull)(~(i0 + t));
                    }
                    pre += (unsigned int)__popcll(m[t]);
                }
            }
        }
    }
    __syncthreads();

    const int pcnt = (int)s_cnt;
    if (pcnt >= TARGET && pcnt <= CAP) {
        // ======== FAST PATH ========
        // ---- P2: refine histogram over prefiltered candidates (range binning) ----
        for (int e = tid; e < pcnt; e += NT) {
            unsigned int k32 = (unsigned int)(cand[e] >> 32);
            atomicAdd(&hist[min((k32 - FAST_KBASE) >> FAST_SHIFT, (unsigned)(NBINS - 1))], 1u);
        }
        __syncthreads();
        suffix_find(hist, wtot, TARGET, tid, &s_T1);
        // ---- P4: compact selected (key >= threshold of bin T1) -> cand2 ----
        {
            const ull thr = ((ull)FAST_KBASE + ((ull)(unsigned int)s_T1 << FAST_SHIFT)) << 32;
            for (int e = tid; e < pcnt; e += NT) {
                ull k = cand[e];
                if (k >= thr) {
                    unsigned int p = atomicAdd(&s_cnt2, 1u);
                    if (p < CAP) cand2[p] = k;     // hist dead; alias safe
                }
            }
        }
        __syncthreads();
    } else {
        // ======== EXACT FALLBACK ========
        {
            const float4* cls4 = (const float4*)cls;
            for (int q = tid; q < NA / 4; q += NT) {
                float4 v = cls4[q];
                unsigned int kx = make_key(v.x), ky = make_key(v.y);
                unsigned int kz = make_key(v.z), kw = make_key(v.w);
                if (kx) atomicAdd(&hist[min((kx - FB_KBASE) >> FB_SHIFT, (unsigned)(NBINS - 1))], 1u);
                if (ky) atomicAdd(&hist[min((ky - FB_KBASE) >> FB_SHIFT, (unsigned)(NBINS - 1))], 1u);
                if (kz) atomicAdd(&hist[min((kz - FB_KBASE) >> FB_SHIFT, (unsigned)(NBINS - 1))], 1u);
                if (kw) atomicAdd(&hist[min((kw - FB_KBASE) >> FB_SHIFT, (unsigned)(NBINS - 1))], 1u);
            }
        }
        __syncthreads();
        suffix_find(hist, wtot, TARGET, tid, &s_T1);
        // collect key >= threshold into cand2 (hist dead after suffix_find barrier)
        {
            const ull thr = (s_T1 < 0) ? 0ull
                : ((ull)FB_KBASE + ((ull)(unsigned int)s_T1 << FB_SHIFT));
            const float4* cls4 = (const float4*)cls;
            for (int q = tid; q < NA / 4; q += NT) {
                float4 v = cls4[q];
                const unsigned int i0 = (unsigned int)q * 4u;
                unsigned int kk[4];
                kk[0] = make_key(v.x); kk[1] = make_key(v.y);
                kk[2] = make_key(v.z); kk[3] = make_key(v.w);
#pragma unroll
                for (int t = 0; t < 4; ++t) {
                    unsigned int d = kk[t];
                    if (d && (ull)d >= thr) {
                        unsigned int p = atomicAdd(&s_cnt2, 1u);
                        if (p < CAP)
                            cand2[p] = ((ull)d << 32) | (ull)(~(i0 + t));
                    }
                }
            }
        }
        __syncthreads();
    }

    const int F = min((int)s_cnt2, CAP);
    const int numSel = min(F, TOPK);

    // ---- P5a: exact sigmoid rekey (s_bits desc, idx asc) for F candidates ----
    for (int e = tid; e < F; e += NT) {
        ull k = cand2[e];
        float xv = __uint_as_float(mono_inv((unsigned int)(k >> 32)));
        float sv = sigmoidf(xv);
        cand2[e] = ((ull)__float_as_uint(sv) << 32) | (k & 0xFFFFFFFFull);
    }
    __syncthreads();

    // ---- P5b: rank-by-counting (unique keys), b128-vectorized inner loop ----
    for (int e = tid; e < F; e += NT) {
        ull k = cand2[e];
        int rank = 0;
        int o = 0;
#pragma unroll 2
        for (; o + 4 <= F; o += 4) {
            ulonglong2 p0 = *(const ulonglong2*)&cand2[o];
            ulonglong2 p1 = *(const ulonglong2*)&cand2[o + 2];
            rank += (p0.x > k) + (p0.y > k) + (p1.x > k) + (p1.y > k);
        }
        for (; o < F; ++o) rank += (cand2[o] > k) ? 1 : 0;
        if (rank < TOPK) skey[rank] = k;   // cand region dead after P4
    }
    __syncthreads();

    // ---- P6a: gather boxes (cxcywh -> xyxy) as float4 ----
    for (int r = tid; r < numSel; r += NT) {
        ull k = skey[r];
        unsigned int i = ~(unsigned int)(k & 0xFFFFFFFFull);
        float cx = box[i];
        float cy = box[NA + i];
        float w  = box[2 * NA + i];
        float h  = box[3 * NA + i];
        float hw = w * 0.5f, hh = h * 0.5f;
        box4[r] = float4{cx - hw, cy - hh, cx + hw, cy + hh};
        bvv[r] = __uint_as_float((unsigned int)(k >> 32));
    }
    __syncthreads();   // skey consumed; sup region (aliases skey/cand2) now writable

    // ---- P6b: zero supmask ----
    for (int t = tid; t < TOPK * 5; t += NT) sup[t] = 0ull;
    __syncthreads();

    // ---- P7: suppression masks; columns cached in const-indexed registers
    //      (wave-uniform skip keeps them in VGPRs); next-row prefetch pipeline ----
    {
        const int wave = tid >> 6;
        float4 cb[5];
        float ca[5];
#pragma unroll
        for (int w = 0; w < 5; ++w) {
            int j = (w << 6) + lane;
            float4 v = (j < numSel) ? box4[j] : float4{0.f, 0.f, 0.f, 0.f};
            cb[w] = v;
            ca[w] = fmaxf(v.z - v.x, 0.0f) * fmaxf(v.w - v.y, 0.0f);
        }
        int i = wave;
        float4 bi = (i < numSel) ? box4[i] : float4{0.f, 0.f, 0.f, 0.f};
        while (i < numSel) {
            const int inext = i + NW;
            float4 bnext = (inext < numSel) ? box4[inext] : float4{0.f, 0.f, 0.f, 0.f};
            float ai = fmaxf(bi.z - bi.x, 0.0f) * fmaxf(bi.w - bi.y, 0.0f);
            const int w0 = i >> 6;   // wave-uniform
#pragma unroll
            for (int w = 0; w < 5; ++w) {
                if (w < w0) continue;   // uniform branch
                const int j = (w << 6) + lane;
                bool supb = false;
                if (j < numSel && j > i) {
                    float xx1 = fmaxf(bi.x, cb[w].x);
                    float yy1 = fmaxf(bi.y, cb[w].y);
                    float xx2 = fminf(bi.z, cb[w].z);
                    float yy2 = fminf(bi.w, cb[w].w);
                    float iw = fmaxf(xx2 - xx1, 0.0f);
                    float ih = fmaxf(yy2 - yy1, 0.0f);
                    float inter = iw * ih;
                    float un = ai + ca[w] - inter;
                    float iou = inter / fmaxf(un, 1e-9f);
                    supb = iou > IOU_T;
                }
                ull bal = __ballot(supb);
                if (lane == 0) sup[i * 5 + w] = bal;
            }
            bi = bnext;
            i = inext;
        }
    }
    __syncthreads();

    // ---- P8: greedy scan, wave 0, register-resident via readlane broadcast.
    //      Each lane pre-loads its row's 5 mask words; the 300-step loop has no
    //      LDS access (replaces thread-0 LDS chain: ~36k -> ~10k cycles). ----
    if (tid < 64) {
        ull rem[5] = {0ull, 0ull, 0ull, 0ull, 0ull};
#pragma unroll
        for (int w = 0; w < 5; ++w) {
            int r = (w << 6) + lane;
            bool valid = r < numSel;
            ull a0 = valid ? sup[r * 5 + 0] : 0ull;
            ull a1 = valid ? sup[r * 5 + 1] : 0ull;
            ull a2 = valid ? sup[r * 5 + 2] : 0ull;
            ull a3 = valid ? sup[r * 5 + 3] : 0ull;
            ull a4 = valid ? sup[r * 5 + 4] : 0ull;
            int nIn = numSel - (w << 6);
            nIn = nIn < 0 ? 0 : (nIn > 64 ? 64 : nIn);
            for (int i = 0; i < nIn; ++i) {
                if (!((rem[w] >> i) & 1ull)) {   // uniform (rem identical on all lanes)
                    rem[0] |= readlane64(a0, i);
                    rem[1] |= readlane64(a1, i);
                    rem[2] |= readlane64(a2, i);
                    rem[3] |= readlane64(a3, i);
                    rem[4] |= readlane64(a4, i);
                }
            }
            if (lane == 0) keepw[w] = ~rem[w];
        }
    }
    __syncthreads();

    // ---- P9: write output rows (3x float2 per row) ----
    float* outp = out + ((size_t)b * NC + c) * (TOPK * 6);
    for (int r = tid; r < TOPK; r += NT) {
        float x1 = 0.f, y1 = 0.f, x2 = 0.f, y2 = 0.f, vv = 0.f, cc = 0.f;
        if (r < numSel && ((keepw[r >> 6] >> (r & 63)) & 1ull)) {
            float4 bb = box4[r];
            x1 = bb.x; y1 = bb.y; x2 = bb.z; y2 = bb.w;
            vv = bvv[r]; cc = (float)c;
        }
        float* row = outp + r * 6;
        *(float2*)(row)     = float2{x1, y1};
        *(float2*)(row + 2) = float2{x2, y2};
        *(float2*)(row + 4) = float2{vv, cc};
    }
}

extern "C" void kernel_launch(void* const* d_in, const int* in_sizes, int n_in,
                              void* d_out, int out_size, void* d_ws, size_t ws_size,
                              hipStream_t stream) {
    const float* in = (const float*)d_in[0];
    float* out = (float*)d_out;
    yolo_post<<<NB * NC, NT, 0, stream>>>(in, out);
}

// Round 10
// 154.875 us; speedup vs baseline: 1.3517x; 1.0308x over previous
//
#include <hip/hip_runtime.h>
#include <cstdint>

#pragma clang fp contract(off)

#define NB      32
#define NC      18
#define NA      8400
#define NCH     (4 + NC)
#define TOPK    300
#define TARGET  316        // TOPK + margin: absorbs sigmoid-tie rank ambiguity
#define NBINS   2048
#define CAP     1024
#define CONF    0.25f
#define IOU_T   0.45f
#define NT      512
#define NW      (NT / 64)
// Prefilter: N(0,1) logits, top-316 cutoff ~1.75 +- 0.1; count(x>1.4) in [553,803] (5-sigma).
// Fast path requires TARGET <= s_cnt <= CAP, else exact fallback.
#define PREF_X  1.4f
// sigmoid(x) > 0.25  <=>  x > -ln(3). Outside [XLO,XHI] analytic compare is exact.
#define XHI     (-1.0984f)
#define XLO     (-1.0988f)

// Fast-path binning: keys (mono_key of x>1.4) start at 0xBFB33333.
#define FAST_KBASE 0xBFB00000u
#define FAST_SHIFT 14
// Fallback binning: conf_pass keys start ~0x40735C26.
#define FB_KBASE   0x40000000u
#define FB_SHIFT   21

// Exact div-free IoU compare: RN_f32(inter/D) > 0.45f  <=>  inter > M45*D.
// c45 = fp32(0.45) = 0x3EE66666 = 0xE66666/2^25. Midpoint to next float:
// M45 = c45 + 2^-26 = 30198989/2^26 (25-bit mantissa -> exact f64; x 24-bit D
// -> 49-bit product, exact f64). Tie inter/D == M45 rounds-to-even -> c45
// (mantissa even), i.e. NOT >, matching strict real compare. Bit-exact.
#define M45 (30198989.0 / 67108864.0)

typedef unsigned long long ull;

__device__ __forceinline__ float sigmoidf(float x) {
    return 1.0f / (1.0f + expf(-x));
}
__device__ __forceinline__ unsigned int mono_key(unsigned int bits) {
    return (bits & 0x80000000u) ? ~bits : (bits | 0x80000000u);
}
__device__ __forceinline__ unsigned int mono_inv(unsigned int key) {
    return (key & 0x80000000u) ? (key ^ 0x80000000u) : ~key;
}
__device__ __forceinline__ bool conf_pass(float x) {
    if (x >= XHI) return true;
    if (x <= XLO) return false;
    return sigmoidf(x) > CONF;   // rare exact band (~1 element per task)
}
__device__ __forceinline__ unsigned int make_key(float x) {
    return conf_pass(x) ? mono_key(__float_as_uint(x)) : 0u;
}
__device__ __forceinline__ ull readlane64(ull v, int i) {
    unsigned lo = (unsigned)__builtin_amdgcn_readlane((int)(unsigned)(v & 0xFFFFFFFFull), i);
    unsigned hi = (unsigned)__builtin_amdgcn_readlane((int)(unsigned)(v >> 32), i);
    return ((ull)hi << 32) | (ull)lo;
}

// Suffix-find over hist: T1 s.t. count(bins > T1) < target <= count(bins >= T1).
// Requires *s_T1 == -1 on entry. Contains barriers (block-uniform flow only).
__device__ __forceinline__ void suffix_find(unsigned int* hist, unsigned int* wtot,
                                            int target, int tid, int* s_T1) {
    const int base = tid * (NBINS / NT);   // 4 bins per thread
    unsigned int v = 0;
#pragma unroll
    for (int k = 0; k < NBINS / NT; ++k) v += hist[base + k];
    const int lane = tid & 63;
    unsigned int s = v;   // inclusive suffix sum within wave
#pragma unroll
    for (int d = 1; d < 64; d <<= 1) {
        unsigned int o = __shfl_down(s, d, 64);
        if (lane + d < 64) s += o;
    }
    if (lane == 0) wtot[tid >> 6] = s;
    __syncthreads();
    unsigned int above_waves = 0;
    for (int wv = (tid >> 6) + 1; wv < NW; ++wv) above_waves += wtot[wv];
    unsigned int acc = (s - v) + above_waves;  // strictly after this thread's chunk
    for (int bin = base + (NBINS / NT) - 1; bin >= base; --bin) {
        unsigned int cnt = hist[bin];
        if (acc < (unsigned int)target && acc + cnt >= (unsigned int)target) *s_T1 = bin;
        acc += cnt;
    }
    __syncthreads();
}

// LDS pool phase-aliasing map (17.6 KB):
//  [0,8192):      hist (P0..suffix) -> cand2 (P4..P5b) -> sup[0:8192) (P7..P8)
//  [8192,16384):  cand (P1..P4) -> skey@8192 (P5b..P6a) -> sup[8192:12000) (P7..P8)
//  [12000,16800): box4 (P6a..P9)
//  [16800,18000): bvv  (P6a..P9)
#define OFF_CAND   8192
#define OFF_SKEY   8192
#define OFF_SUP    0
#define OFF_BOX4   12000
#define OFF_BVV    16800
#define POOL_BYTES 18000

__global__ __launch_bounds__(NT) void yolo_post(const float* __restrict__ in,
                                                float* __restrict__ out) {
    __shared__ __align__(16) unsigned char pool[POOL_BYTES];
    __shared__ unsigned int wtot[NW];
    __shared__ ull keepw[5];
    __shared__ unsigned int s_cnt, s_cnt2;
    __shared__ int s_T1;

    unsigned int* hist = (unsigned int*)pool;
    ull*  cand2 = (ull*)pool;
    ull*  cand  = (ull*)(pool + OFF_CAND);
    ull*  skey  = (ull*)(pool + OFF_SKEY);
    ull*  sup   = (ull*)(pool + OFF_SUP);    // [300][5]
    float4* box4 = (float4*)(pool + OFF_BOX4);
    float*  bvv  = (float*)(pool + OFF_BVV);

    const int tid = threadIdx.x;
    const int lane = tid & 63;
    const ull ltm = (1ull << lane) - 1ull;
    // XCD swizzle: image b -> XCD b%8 (round-robin dispatch over 8 XCDs)
    const int x = blockIdx.x;
    const int b = (x & 7) + 8 * ((x >> 3) & 3);
    const int c = x >> 5;
    const float* cls = in + (size_t)b * NCH * NA + (size_t)(4 + c) * NA;
    const float* box = in + (size_t)b * NCH * NA;

    // ---- P0: zero hist, init counters ----
    for (int i = tid; i < NBINS; i += NT) hist[i] = 0;
    if (tid == 0) { s_cnt = 0; s_cnt2 = 0; s_T1 = -1; }
    __syncthreads();

    // ---- P1: global pass, prefilter x>1.4, wave-aggregated compaction into cand,
    //      refine histogram FUSED into the append (saves the old P2 pass) ----
    {
        const float4* cls4 = (const float4*)cls;
        for (int q = tid; q < NA / 4; q += NT) {
            float4 v = cls4[q];
            const unsigned int i0 = (unsigned int)q * 4u;
            float xs[4] = {v.x, v.y, v.z, v.w};
            ull m[4];
            unsigned int cnt = 0;
#pragma unroll
            for (int t = 0; t < 4; ++t) {
                m[t] = __ballot(xs[t] > PREF_X);
                cnt += (unsigned int)__popcll(m[t]);
            }
            if (cnt) {
                unsigned int base = 0;
                if (lane == 0) base = atomicAdd(&s_cnt, cnt);
                base = (unsigned int)__builtin_amdgcn_readfirstlane((int)base);
                unsigned int pre = 0;
#pragma unroll
                for (int t = 0; t < 4; ++t) {
                    if (xs[t] > PREF_X) {
                        unsigned int mk = mono_key(__float_as_uint(xs[t]));
                        atomicAdd(&hist[min((mk - FAST_KBASE) >> FAST_SHIFT,
                                            (unsigned)(NBINS - 1))], 1u);
                        unsigned int p = base + pre + (unsigned int)__popcll(m[t] & ltm);
                        if (p < CAP)
                            cand[p] = ((ull)mk << 32) | (ull)(~(i0 + t));
                    }
                    pre += (unsigned int)__popcll(m[t]);
                }
            }
        }
    }
    __syncthreads();

    const int pcnt = (int)s_cnt;
    if (pcnt >= TARGET && pcnt <= CAP) {
        // ======== FAST PATH ========
        suffix_find(hist, wtot, TARGET, tid, &s_T1);
        // ---- P4: compact selected -> cand2 with FUSED exact-sigmoid rekey,
        //      wave-aggregated counter (saves the old P5a pass) ----
        {
            const ull thr = ((ull)FAST_KBASE + ((ull)(unsigned int)s_T1 << FAST_SHIFT)) << 32;
            const int iters = (pcnt + NT - 1) / NT;
            for (int it = 0; it < iters; ++it) {
                int e = tid + it * NT;
                bool act = e < pcnt;
                ull k = act ? cand[e] : 0ull;
                bool sel = act && (k >= thr);
                ull mb = __ballot(sel);
                unsigned int cnt = (unsigned int)__popcll(mb);
                if (cnt) {
                    unsigned int basep = 0;
                    if (lane == 0) basep = atomicAdd(&s_cnt2, cnt);
                    basep = (unsigned int)__builtin_amdgcn_readfirstlane((int)basep);
                    if (sel) {
                        float xv = __uint_as_float(mono_inv((unsigned int)(k >> 32)));
                        float sv = sigmoidf(xv);
                        unsigned int p = basep + (unsigned int)__popcll(mb & ltm);
                        if (p < CAP)
                            cand2[p] = ((ull)__float_as_uint(sv) << 32) |
                                       (k & 0xFFFFFFFFull);
                    }
                }
            }
        }
        __syncthreads();
    } else {
        // ======== EXACT FALLBACK (rare) ========
        // hist was polluted by P1's fused histogram -> re-zero first.
        __syncthreads();
        for (int i = tid; i < NBINS; i += NT) hist[i] = 0;
        __syncthreads();
        {
            const float4* cls4 = (const float4*)cls;
            for (int q = tid; q < NA / 4; q += NT) {
                float4 v = cls4[q];
                unsigned int kx = make_key(v.x), ky = make_key(v.y);
                unsigned int kz = make_key(v.z), kw = make_key(v.w);
                if (kx) atomicAdd(&hist[min((kx - FB_KBASE) >> FB_SHIFT, (unsigned)(NBINS - 1))], 1u);
                if (ky) atomicAdd(&hist[min((ky - FB_KBASE) >> FB_SHIFT, (unsigned)(NBINS - 1))], 1u);
                if (kz) atomicAdd(&hist[min((kz - FB_KBASE) >> FB_SHIFT, (unsigned)(NBINS - 1))], 1u);
                if (kw) atomicAdd(&hist[min((kw - FB_KBASE) >> FB_SHIFT, (unsigned)(NBINS - 1))], 1u);
            }
        }
        __syncthreads();
        suffix_find(hist, wtot, TARGET, tid, &s_T1);
        // collect key >= threshold into cand2, sigmoid fused at store
        {
            const ull thr = (s_T1 < 0) ? 0ull
                : ((ull)FB_KBASE + ((ull)(unsigned int)s_T1 << FB_SHIFT));
            const float4* cls4 = (const float4*)cls;
            for (int q = tid; q < NA / 4; q += NT) {
                float4 v = cls4[q];
                const unsigned int i0 = (unsigned int)q * 4u;
                float xs[4] = {v.x, v.y, v.z, v.w};
#pragma unroll
                for (int t = 0; t < 4; ++t) {
                    unsigned int d = make_key(xs[t]);
                    if (d && (ull)d >= thr) {
                        unsigned int p = atomicAdd(&s_cnt2, 1u);
                        if (p < CAP) {
                            float sv = sigmoidf(xs[t]);
                            cand2[p] = ((ull)__float_as_uint(sv) << 32) |
                                       (ull)(~(i0 + t));
                        }
                    }
                }
            }
        }
        __syncthreads();
    }

    const int F = min((int)s_cnt2, CAP);
    const int numSel = min(F, TOPK);

    // ---- P5b: rank-by-counting (unique keys via ~idx), b128-vectorized ----
    for (int e = tid; e < F; e += NT) {
        ull k = cand2[e];
        int rank = 0;
        int o = 0;
#pragma unroll 2
        for (; o + 4 <= F; o += 4) {
            ulonglong2 p0 = *(const ulonglong2*)&cand2[o];
            ulonglong2 p1 = *(const ulonglong2*)&cand2[o + 2];
            rank += (p0.x > k) + (p0.y > k) + (p1.x > k) + (p1.y > k);
        }
        for (; o < F; ++o) rank += (cand2[o] > k) ? 1 : 0;
        if (rank < TOPK) skey[rank] = k;   // disjoint region, no mid-phase barrier
    }
    __syncthreads();

    // ---- P6a: gather boxes (cxcywh -> xyxy) as float4 ----
    for (int r = tid; r < numSel; r += NT) {
        ull k = skey[r];
        unsigned int i = ~(unsigned int)(k & 0xFFFFFFFFull);
        float cx = box[i];
        float cy = box[NA + i];
        float w  = box[2 * NA + i];
        float h  = box[3 * NA + i];
        float hw = w * 0.5f, hh = h * 0.5f;
        box4[r] = float4{cx - hw, cy - hh, cx + hw, cy + hh};
        bvv[r] = __uint_as_float((unsigned int)(k >> 32));
    }
    __syncthreads();   // skey consumed; sup region (aliases skey/cand2) now writable

    // ---- P7: suppression masks; full-row writes (incl. zero words -> no pre-zero
    //      pass). Columns in const-indexed registers; next-row prefetch; exact
    //      f64 multiply-compare replaces the IEEE fp32 div chain. ----
    {
        const int wave = tid >> 6;
        float4 cb[5];
        float ca[5];
#pragma unroll
        for (int w = 0; w < 5; ++w) {
            int j = (w << 6) + lane;
            float4 v = (j < numSel) ? box4[j] : float4{0.f, 0.f, 0.f, 0.f};
            cb[w] = v;
            ca[w] = fmaxf(v.z - v.x, 0.0f) * fmaxf(v.w - v.y, 0.0f);
        }
        int i = wave;
        float4 bi = (i < numSel) ? box4[i] : float4{0.f, 0.f, 0.f, 0.f};
        while (i < numSel) {
            const int inext = i + NW;
            float4 bnext = (inext < numSel) ? box4[inext] : float4{0.f, 0.f, 0.f, 0.f};
            float ai = fmaxf(bi.z - bi.x, 0.0f) * fmaxf(bi.w - bi.y, 0.0f);
            const int w0 = i >> 6;   // wave-uniform
#pragma unroll
            for (int w = 0; w < 5; ++w) {
                ull bal = 0ull;
                if (w >= w0) {       // uniform branch
                    const int j = (w << 6) + lane;
                    bool supb = false;
                    if (j < numSel && j > i) {
                        float xx1 = fmaxf(bi.x, cb[w].x);
                        float yy1 = fmaxf(bi.y, cb[w].y);
                        float xx2 = fminf(bi.z, cb[w].z);
                        float yy2 = fminf(bi.w, cb[w].w);
                        float iw = fmaxf(xx2 - xx1, 0.0f);
                        float ih = fmaxf(yy2 - yy1, 0.0f);
                        float inter = iw * ih;
                        float un = ai + ca[w] - inter;
                        float D = fmaxf(un, 1e-9f);
                        supb = (double)inter > M45 * (double)D;  // == RN(inter/D) > 0.45f
                    }
                    bal = __ballot(supb);
                }
                if (lane == 0) sup[i * 5 + w] = bal;
            }
            bi = bnext;
            i = inext;
        }
    }
    __syncthreads();

    // ---- P8: greedy scan, wave 0, register-resident via readlane broadcast ----
    if (tid < 64) {
        ull rem[5] = {0ull, 0ull, 0ull, 0ull, 0ull};
#pragma unroll
        for (int w = 0; w < 5; ++w) {
            int r = (w << 6) + lane;
            bool valid = r < numSel;
            ull a0 = valid ? sup[r * 5 + 0] : 0ull;
            ull a1 = valid ? sup[r * 5 + 1] : 0ull;
            ull a2 = valid ? sup[r * 5 + 2] : 0ull;
            ull a3 = valid ? sup[r * 5 + 3] : 0ull;
            ull a4 = valid ? sup[r * 5 + 4] : 0ull;
            int nIn = numSel - (w << 6);
            nIn = nIn < 0 ? 0 : (nIn > 64 ? 64 : nIn);
            for (int i = 0; i < nIn; ++i) {
                if (!((rem[w] >> i) & 1ull)) {   // uniform (rem identical on all lanes)
                    rem[0] |= readlane64(a0, i);
                    rem[1] |= readlane64(a1, i);
                    rem[2] |= readlane64(a2, i);
                    rem[3] |= readlane64(a3, i);
                    rem[4] |= readlane64(a4, i);
                }
            }
            if (lane == 0) keepw[w] = ~rem[w];
        }
    }
    __syncthreads();

    // ---- P9: write output rows (3x float2 per row) ----
    float* outp = out + ((size_t)b * NC + c) * (TOPK * 6);
    for (int r = tid; r < TOPK; r += NT) {
        float x1 = 0.f, y1 = 0.f, x2 = 0.f, y2 = 0.f, vv = 0.f, cc = 0.f;
        if (r < numSel && ((keepw[r >> 6] >> (r & 63)) & 1ull)) {
            float4 bb = box4[r];
            x1 = bb.x; y1 = bb.y; x2 = bb.z; y2 = bb.w;
            vv = bvv[r]; cc = (float)c;
        }
        float* row = outp + r * 6;
        *(float2*)(row)     = float2{x1, y1};
        *(float2*)(row + 2) = float2{x2, y2};
        *(float2*)(row + 4) = float2{vv, cc};
    }
}

extern "C" void kernel_launch(void* const* d_in, const int* in_sizes, int n_in,
                              void* d_out, int out_size, void* d_ws, size_t ws_size,
                              hipStream_t stream) {
    const float* in = (const float*)d_in[0];
    float* out = (float*)d_out;
    yolo_post<<<NB * NC, NT, 0, stream>>>(in, out);
}

// Round 11
// 148.287 us; speedup vs baseline: 1.4118x; 1.0444x over previous
//
#include <hip/hip_runtime.h>
#include <cstdint>

#pragma clang fp contract(off)

#define NB      32
#define NC      18
#define NA      8400
#define NCH     (4 + NC)
#define NTASK   (NB * NC)      // 576
#define TOPK    300
#define TARGET  316        // TOPK + margin: absorbs sigmoid-tie rank ambiguity
#define NBINS   2048
#define CAP     1024
#define CONF    0.25f
#define IOU_T   0.45f
#define NT      512
#define NW      (NT / 64)
// Prefilter: N(0,1) logits, top-316 cutoff ~1.75 +- 0.1; count(x>1.4) in [553,803] (5-sigma).
// Fast path requires TARGET <= s_cnt <= CAP, else exact fallback.
#define PREF_X  1.4f
// sigmoid(x) > 0.25  <=>  x > -ln(3). Outside [XLO,XHI] analytic compare is exact.
#define XHI     (-1.0984f)
#define XLO     (-1.0988f)

// Fast-path binning: keys (mono_key of x>1.4) start at 0xBFB33333.
#define FAST_KBASE 0xBFB00000u
#define FAST_SHIFT 14
// Fallback binning: conf_pass keys start ~0x40735C26.
#define FB_KBASE   0x40000000u
#define FB_SHIFT   21

// Exact div-free IoU compare: RN_f32(inter/D) > 0.45f  <=>  inter > M45*D.
// M45 = fp32(0.45) + 2^-26 (25-bit mantissa, exact in f64; x 24-bit D -> exact
// 49-bit product). Tie rounds-to-even back to 0.45f => not >, matching. Bit-exact.
#define M45 (30198989.0 / 67108864.0)

// Workspace layout (10.37 MB):
#define WS_BOX 0                                  // float4[576][300]  2764800 B
#define WS_VAL (NTASK * TOPK * 16)                // float [576][300]   691200 B
#define WS_SUP (WS_VAL + NTASK * TOPK * 4)        // ull   [576][300][5] 6912000 B
#define WS_CNT (WS_SUP + NTASK * TOPK * 5 * 8)    // int   [576]          2304 B

typedef unsigned long long ull;

__device__ __forceinline__ float sigmoidf(float x) {
    return 1.0f / (1.0f + expf(-x));
}
__device__ __forceinline__ unsigned int mono_key(unsigned int bits) {
    return (bits & 0x80000000u) ? ~bits : (bits | 0x80000000u);
}
__device__ __forceinline__ unsigned int mono_inv(unsigned int key) {
    return (key & 0x80000000u) ? (key ^ 0x80000000u) : ~key;
}
__device__ __forceinline__ bool conf_pass(float x) {
    if (x >= XHI) return true;
    if (x <= XLO) return false;
    return sigmoidf(x) > CONF;   // rare exact band (~1 element per task)
}
__device__ __forceinline__ unsigned int make_key(float x) {
    return conf_pass(x) ? mono_key(__float_as_uint(x)) : 0u;
}
__device__ __forceinline__ ull readlane64(ull v, int i) {
    unsigned lo = (unsigned)__builtin_amdgcn_readlane((int)(unsigned)(v & 0xFFFFFFFFull), i);
    unsigned hi = (unsigned)__builtin_amdgcn_readlane((int)(unsigned)(v >> 32), i);
    return ((ull)hi << 32) | (ull)lo;
}

// Suffix-find over hist: T1 s.t. count(bins > T1) < target <= count(bins >= T1).
__device__ __forceinline__ void suffix_find(unsigned int* hist, unsigned int* wtot,
                                            int target, int tid, int* s_T1) {
    const int base = tid * (NBINS / NT);
    unsigned int v = 0;
#pragma unroll
    for (int k = 0; k < NBINS / NT; ++k) v += hist[base + k];
    const int lane = tid & 63;
    unsigned int s = v;
#pragma unroll
    for (int d = 1; d < 64; d <<= 1) {
        unsigned int o = __shfl_down(s, d, 64);
        if (lane + d < 64) s += o;
    }
    if (lane == 0) wtot[tid >> 6] = s;
    __syncthreads();
    unsigned int above_waves = 0;
    for (int wv = (tid >> 6) + 1; wv < NW; ++wv) above_waves += wtot[wv];
    unsigned int acc = (s - v) + above_waves;
    for (int bin = base + (NBINS / NT) - 1; bin >= base; --bin) {
        unsigned int cnt = hist[bin];
        if (acc < (unsigned int)target && acc + cnt >= (unsigned int)target) *s_T1 = bin;
        acc += cnt;
    }
    __syncthreads();
}

// K1 LDS: [0,8192) hist -> cand2 ; [8192,16384) cand
#define OFF_CAND   8192
#define POOL1_BYTES 16384

// ============ K1: top-300 select (per task), gather fused into rank write ============
__global__ __launch_bounds__(NT) void k_select(const float* __restrict__ in,
                                               float4* __restrict__ wsBox,
                                               float* __restrict__ wsVal,
                                               int* __restrict__ wsCnt) {
    __shared__ __align__(16) unsigned char pool[POOL1_BYTES];
    __shared__ unsigned int wtot[NW];
    __shared__ unsigned int s_cnt, s_cnt2;
    __shared__ int s_T1;

    unsigned int* hist = (unsigned int*)pool;
    ull* cand2 = (ull*)pool;
    ull* cand  = (ull*)(pool + OFF_CAND);

    const int tid = threadIdx.x;
    const int lane = tid & 63;
    const ull ltm = (1ull << lane) - 1ull;
    const int t = blockIdx.x;
    // XCD swizzle: image b -> XCD b%8
    const int b = (t & 7) + 8 * ((t >> 3) & 3);
    const int c = t >> 5;
    const float* cls = in + (size_t)b * NCH * NA + (size_t)(4 + c) * NA;
    const float* box = in + (size_t)b * NCH * NA;

    for (int i = tid; i < NBINS; i += NT) hist[i] = 0;
    if (tid == 0) { s_cnt = 0; s_cnt2 = 0; s_T1 = -1; }
    __syncthreads();

    // P1: prefilter x>1.4, wave-aggregated compaction, fused refine histogram
    {
        const float4* cls4 = (const float4*)cls;
        for (int q = tid; q < NA / 4; q += NT) {
            float4 v = cls4[q];
            const unsigned int i0 = (unsigned int)q * 4u;
            float xs[4] = {v.x, v.y, v.z, v.w};
            ull m[4];
            unsigned int cnt = 0;
#pragma unroll
            for (int u = 0; u < 4; ++u) {
                m[u] = __ballot(xs[u] > PREF_X);
                cnt += (unsigned int)__popcll(m[u]);
            }
            if (cnt) {
                unsigned int base = 0;
                if (lane == 0) base = atomicAdd(&s_cnt, cnt);
                base = (unsigned int)__builtin_amdgcn_readfirstlane((int)base);
                unsigned int pre = 0;
#pragma unroll
                for (int u = 0; u < 4; ++u) {
                    if (xs[u] > PREF_X) {
                        unsigned int mk = mono_key(__float_as_uint(xs[u]));
                        atomicAdd(&hist[min((mk - FAST_KBASE) >> FAST_SHIFT,
                                            (unsigned)(NBINS - 1))], 1u);
                        unsigned int p = base + pre + (unsigned int)__popcll(m[u] & ltm);
                        if (p < CAP)
                            cand[p] = ((ull)mk << 32) | (ull)(~(i0 + u));
                    }
                    pre += (unsigned int)__popcll(m[u]);
                }
            }
        }
    }
    __syncthreads();

    const int pcnt = (int)s_cnt;
    if (pcnt >= TARGET && pcnt <= CAP) {
        // ---- fast path ----
        suffix_find(hist, wtot, TARGET, tid, &s_T1);
        const ull thr = ((ull)FAST_KBASE + ((ull)(unsigned int)s_T1 << FAST_SHIFT)) << 32;
        const int iters = (pcnt + NT - 1) / NT;
        for (int it = 0; it < iters; ++it) {
            int e = tid + it * NT;
            bool act = e < pcnt;
            ull k = act ? cand[e] : 0ull;
            bool sel = act && (k >= thr);
            ull mb = __ballot(sel);
            unsigned int cnt = (unsigned int)__popcll(mb);
            if (cnt) {
                unsigned int basep = 0;
                if (lane == 0) basep = atomicAdd(&s_cnt2, cnt);
                basep = (unsigned int)__builtin_amdgcn_readfirstlane((int)basep);
                if (sel) {
                    float xv = __uint_as_float(mono_inv((unsigned int)(k >> 32)));
                    float sv = sigmoidf(xv);
                    unsigned int p = basep + (unsigned int)__popcll(mb & ltm);
                    if (p < CAP)
                        cand2[p] = ((ull)__float_as_uint(sv) << 32) | (k & 0xFFFFFFFFull);
                }
            }
        }
        __syncthreads();
    } else {
        // ---- exact fallback (rare): re-zero hist, full conf_pass histogram ----
        __syncthreads();
        for (int i = tid; i < NBINS; i += NT) hist[i] = 0;
        __syncthreads();
        {
            const float4* cls4 = (const float4*)cls;
            for (int q = tid; q < NA / 4; q += NT) {
                float4 v = cls4[q];
                unsigned int kx = make_key(v.x), ky = make_key(v.y);
                unsigned int kz = make_key(v.z), kw = make_key(v.w);
                if (kx) atomicAdd(&hist[min((kx - FB_KBASE) >> FB_SHIFT, (unsigned)(NBINS - 1))], 1u);
                if (ky) atomicAdd(&hist[min((ky - FB_KBASE) >> FB_SHIFT, (unsigned)(NBINS - 1))], 1u);
                if (kz) atomicAdd(&hist[min((kz - FB_KBASE) >> FB_SHIFT, (unsigned)(NBINS - 1))], 1u);
                if (kw) atomicAdd(&hist[min((kw - FB_KBASE) >> FB_SHIFT, (unsigned)(NBINS - 1))], 1u);
            }
        }
        __syncthreads();
        suffix_find(hist, wtot, TARGET, tid, &s_T1);
        {
            const ull thr = (s_T1 < 0) ? 0ull
                : ((ull)FB_KBASE + ((ull)(unsigned int)s_T1 << FB_SHIFT));
            const float4* cls4 = (const float4*)cls;
            for (int q = tid; q < NA / 4; q += NT) {
                float4 v = cls4[q];
                const unsigned int i0 = (unsigned int)q * 4u;
                float xs[4] = {v.x, v.y, v.z, v.w};
#pragma unroll
                for (int u = 0; u < 4; ++u) {
                    unsigned int d = make_key(xs[u]);
                    if (d && (ull)d >= thr) {
                        unsigned int p = atomicAdd(&s_cnt2, 1u);
                        if (p < CAP) {
                            float sv = sigmoidf(xs[u]);
                            cand2[p] = ((ull)__float_as_uint(sv) << 32) | (ull)(~(i0 + u));
                        }
                    }
                }
            }
        }
        __syncthreads();
    }

    const int F = min((int)s_cnt2, CAP);
    const int numSel = min(F, TOPK);

    // rank-by-counting (unique keys via ~idx) + FUSED box gather to ws
    float4* tBox = wsBox + (size_t)t * TOPK;
    float*  tVal = wsVal + (size_t)t * TOPK;
    for (int e = tid; e < F; e += NT) {
        ull k = cand2[e];
        int rank = 0;
        int o = 0;
#pragma unroll 2
        for (; o + 4 <= F; o += 4) {
            ulonglong2 p0 = *(const ulonglong2*)&cand2[o];
            ulonglong2 p1 = *(const ulonglong2*)&cand2[o + 2];
            rank += (p0.x > k) + (p0.y > k) + (p1.x > k) + (p1.y > k);
        }
        for (; o < F; ++o) rank += (cand2[o] > k) ? 1 : 0;
        if (rank < TOPK) {
            unsigned int i = ~(unsigned int)(k & 0xFFFFFFFFull);
            float cx = box[i];
            float cy = box[NA + i];
            float w  = box[2 * NA + i];
            float h  = box[3 * NA + i];
            float hw = w * 0.5f, hh = h * 0.5f;
            tBox[rank] = float4{cx - hw, cy - hh, cx + hw, cy + hh};
            tVal[rank] = __uint_as_float((unsigned int)(k >> 32));
        }
    }
    if (tid == 0) wsCnt[t] = numSel;
}

// ============ K2: suppression-mask build, 2880 uniform blocks ============
__global__ __launch_bounds__(256) void k_mask(const float4* __restrict__ wsBox,
                                              const int* __restrict__ wsCnt,
                                              ull* __restrict__ wsSup) {
    const int t = blockIdx.x;
    const int g = blockIdx.y;          // row group: rows [64g, 64g+64)
    const int tid = threadIdx.x;
    const int lane = tid & 63;
    const int wave = tid >> 6;

    __shared__ float4 bs[TOPK];
    __shared__ float  ar[TOPK];
    __shared__ int s_n;
    if (tid == 0) s_n = wsCnt[t];
    __syncthreads();
    const int numSel = s_n;

    const float4* tb = wsBox + (size_t)t * TOPK;
    for (int r = tid; r < TOPK; r += 256) {
        float4 v = (r < numSel) ? tb[r] : float4{0.f, 0.f, 0.f, 0.f};
        bs[r] = v;
        ar[r] = fmaxf(v.z - v.x, 0.f) * fmaxf(v.w - v.y, 0.f);
    }
    __syncthreads();

    float4 cb[5];
    float ca[5];
#pragma unroll
    for (int w = 0; w < 5; ++w) {
        int j = (w << 6) + lane;
        bool v = j < TOPK;
        cb[w] = v ? bs[j] : float4{0.f, 0.f, 0.f, 0.f};
        ca[w] = v ? ar[j] : 0.f;
    }

    const int r0 = g << 6;
    const int rend = min(r0 + 64, TOPK);
    ull* supt = wsSup + (size_t)t * (TOPK * 5);
    for (int r = r0 + wave; r < rend; r += 4) {
        const bool vrow = r < numSel;      // wave-uniform
        float4 bi = bs[r];
        float ai = ar[r];
#pragma unroll
        for (int w = 0; w < 5; ++w) {
            ull bal = 0ull;
            if (w >= g && vrow) {          // uniform branch
                const int j = (w << 6) + lane;
                bool supb = false;
                if (j < numSel && j > r) {
                    float xx1 = fmaxf(bi.x, cb[w].x);
                    float yy1 = fmaxf(bi.y, cb[w].y);
                    float xx2 = fminf(bi.z, cb[w].z);
                    float yy2 = fminf(bi.w, cb[w].w);
                    float iw = fmaxf(xx2 - xx1, 0.0f);
                    float ih = fmaxf(yy2 - yy1, 0.0f);
                    float inter = iw * ih;
                    float un = ai + ca[w] - inter;
                    float D = fmaxf(un, 1e-9f);
                    supb = (double)inter > M45 * (double)D;  // == RN(inter/D) > 0.45f
                }
                bal = __ballot(supb);
            }
            if (lane == 0) supt[r * 5 + w] = bal;
        }
    }
}

// ============ K3: greedy scan (register-resident) + output write ============
__global__ __launch_bounds__(64) void k_scan_out(const float4* __restrict__ wsBox,
                                                 const float* __restrict__ wsVal,
                                                 const int* __restrict__ wsCnt,
                                                 const ull* __restrict__ wsSup,
                                                 float* __restrict__ out) {
    const int t = blockIdx.x;
    const int lane = threadIdx.x;
    const int numSel = wsCnt[t];
    const ull* supt = wsSup + (size_t)t * (TOPK * 5);

    // lane holds rows {lane, 64+lane, ..., 256+lane}: 5 words each
    ull a[5][5];
#pragma unroll
    for (int w = 0; w < 5; ++w) {
        int r = (w << 6) + lane;
        bool v = r < TOPK;
#pragma unroll
        for (int x = 0; x < 5; ++x)
            a[w][x] = v ? supt[r * 5 + x] : 0ull;
    }

    ull rem[5] = {0ull, 0ull, 0ull, 0ull, 0ull};
#pragma unroll
    for (int w = 0; w < 5; ++w) {
        int nIn = numSel - (w << 6);
        nIn = nIn < 0 ? 0 : (nIn > 64 ? 64 : nIn);
        for (int i = 0; i < nIn; ++i) {
            if (!((rem[w] >> i) & 1ull)) {   // uniform: rem identical on all lanes
                rem[0] |= readlane64(a[w][0], i);
                rem[1] |= readlane64(a[w][1], i);
                rem[2] |= readlane64(a[w][2], i);
                rem[3] |= readlane64(a[w][3], i);
                rem[4] |= readlane64(a[w][4], i);
            }
        }
    }

    const int b = (t & 7) + 8 * ((t >> 3) & 3);
    const int c = t >> 5;
    float* outp = out + ((size_t)b * NC + c) * (TOPK * 6);
    const float4* tb = wsBox + (size_t)t * TOPK;
    const float* tv = wsVal + (size_t)t * TOPK;
#pragma unroll
    for (int w = 0; w < 5; ++w) {
        int r = (w << 6) + lane;
        if (r < TOPK) {
            float x1 = 0.f, y1 = 0.f, x2 = 0.f, y2 = 0.f, vv = 0.f, cc = 0.f;
            if (r < numSel && ((~rem[w] >> lane) & 1ull)) {
                float4 bb = tb[r];
                x1 = bb.x; y1 = bb.y; x2 = bb.z; y2 = bb.w;
                vv = tv[r]; cc = (float)c;
            }
            float* row = outp + r * 6;
            *(float2*)(row)     = float2{x1, y1};
            *(float2*)(row + 2) = float2{x2, y2};
            *(float2*)(row + 4) = float2{vv, cc};
        }
    }
}

extern "C" void kernel_launch(void* const* d_in, const int* in_sizes, int n_in,
                              void* d_out, int out_size, void* d_ws, size_t ws_size,
                              hipStream_t stream) {
    const float* in = (const float*)d_in[0];
    float* out = (float*)d_out;
    char* ws = (char*)d_ws;
    float4* wsBox = (float4*)(ws + WS_BOX);
    float*  wsVal = (float*)(ws + WS_VAL);
    ull*    wsSup = (ull*)(ws + WS_SUP);
    int*    wsCnt = (int*)(ws + WS_CNT);

    k_select<<<NTASK, NT, 0, stream>>>(in, wsBox, wsVal, wsCnt);
    k_mask<<<dim3(NTASK, 5), 256, 0, stream>>>(wsBox, wsCnt, wsSup);
    k_scan_out<<<NTASK, 64, 0, stream>>>(wsBox, wsVal, wsCnt, wsSup, out);
}